// Round 16
// baseline (677.232 us; speedup 1.0000x reference)
//
#include <hip/hip_runtime.h>
#include <hip/hip_bf16.h>
#include <cstdint>
#include <cstddef>

// ---------------------------------------------------------------------------
// RelativePositionMultiHeadAttention  (B=32,G=64,P=64,D=384,H=12,DH=32)
// R16: MEGA-FUSION. One block per bg (2048 x 768thr, 144 KB LDS, 1 blk/CU).
//   x staged ONCE (persistent region); 3-pass QKV+attn loop accumulates
//   attention output in LDS ao[64][384] (stage-swizzled); final merge GEMM
//   reads ao from LDS and writes fp32 out directly. Kills: merge kernel
//   (60us serial), attnbuf 201MB round-trip, 2/3 x restages. ps aliases qs
//   behind a barrier (R7-proven). Waves 8-11 run ahead into next pass GEMM
//   during attention (idle-fill). Occupancy deprioritized (R15: not a lever).
// ---------------------------------------------------------------------------

typedef __bf16 bf16_t;
typedef __bf16 bf16x8 __attribute__((ext_vector_type(8)));
typedef float  f32x4  __attribute__((ext_vector_type(4)));

#define MFMA16(A, B, C) __builtin_amdgcn_mfma_f32_16x16x32_bf16((A), (B), (C), 0, 0, 0)

#define SCALE  0.051031036307982884f  // 384^-0.5
#define LOG2E  1.4426950408889634f

// lgkmcnt-only barrier (cross-wave deps are LDS-only in this kernel)
#define BAR()  do { asm volatile("s_waitcnt lgkmcnt(0)" ::: "memory"); \
                    __builtin_amdgcn_s_barrier(); } while (0)

// LDS map (bf16 elems), 73728 elems = 144 KB (1 block/CU):
//   xs  @0      [64][384]  x, persistent all passes; 16B-chunk ^(row&7)
//   qs  @24576  [4][64][32] Q (swizzle v2)   -- ps aliases (behind BAR)
//   ks  @32768  [4][64][32] K (swizzle v2)
//   vts @40960  [4][32][64] V^T (chunk^=d&7)
//   ao  @49152  [64][384]  attn-out, same 16B-chunk ^(row&7) swizzle as xs
//   ps  = qs    [8][16][64] per-wave P scratch
// Bank conflicts: ~1.45e7 = b128 wide-op serialization floor (not a lever).

// ---------------------------------------------------------------------------
__global__ void prep_kernel(const float* __restrict__ qkv_w,
                            const float* __restrict__ qkv_b,
                            const float* __restrict__ merge_w,
                            const float* __restrict__ bias_table,
                            const int*   __restrict__ rel_index,
                            bf16_t* __restrict__ qkv_wT,
                            bf16_t* __restrict__ merge_wT,
                            bf16_t* __restrict__ biasx,
                            float*  __restrict__ qkvb_s) {
  int idx = blockIdx.x * 256 + threadIdx.x;
  if (idx < 1152 * 384) {               // qkv_wT[n][k] = qkv_w[k][n] (*scale for K)
    int n = idx / 384, k = idx - n * 384;
    float v = qkv_w[k * 1152 + n];
    if (n >= 384 && n < 768) v *= SCALE;
    qkv_wT[idx] = (bf16_t)v;
    return;
  }
  int i2 = idx - 1152 * 384;
  if (i2 < 384 * 384) {                 // merge_wT[n][k] = merge_w[k][n]
    int n = i2 / 384, k = i2 - n * 384;
    merge_wT[i2] = (bf16_t)merge_w[k * 384 + n];
    return;
  }
  int i3 = i2 - 384 * 384;
  if (i3 < 12 * 64 * 64) {              // biasx[h][i*64+j], bf16
    int h = i3 / 4096, r = i3 - h * 4096;
    biasx[i3] = (bf16_t)bias_table[rel_index[r] * 12 + h];
    return;
  }
  int i4 = i3 - 12 * 64 * 64;
  if (i4 < 1152) {
    float v = qkv_b[i4];
    if (i4 >= 384 && i4 < 768) v *= SCALE;
    qkvb_s[i4] = v;
  }
}

__device__ inline float bflo(unsigned u) {
  union { unsigned x; float f; } v; v.x = u << 16; return v.f;
}
__device__ inline float bfhi(unsigned u) {
  union { unsigned x; float f; } v; v.x = u & 0xffff0000u; return v.f;
}

// ---------------------------------------------------------------------------
// mega kernel: stage x -> {GEMM -> BAR -> epilogue -> BAR -> attn-loads ->
// BAR -> softmax/PV -> ao} x3 -> BAR -> merge GEMM -> out.
// ---------------------------------------------------------------------------
__global__ void __launch_bounds__(768, 6)
mega_kernel(const float*  __restrict__ x,
            const bf16_t* __restrict__ wT,
            const float*  __restrict__ qbias,
            const bf16_t* __restrict__ biasx,
            const bf16_t* __restrict__ mwT,
            const float*  __restrict__ mb,
            float* __restrict__ out) {
  extern __shared__ char smem_raw[];
  bf16_t* lds = (bf16_t*)smem_raw;
  bf16_t* xs  = lds;            // [64][384] persistent
  bf16_t* qs  = lds + 24576;    // [4][64][32] swizzle v2 (ps aliases)
  bf16_t* ks  = lds + 32768;    // [4][64][32] swizzle v2
  bf16_t* vts = lds + 40960;    // [4][32][64] chunk^=d&7
  bf16_t* ao  = lds + 49152;    // [64][384] stage-swizzled
  bf16_t* ps  = qs;             // alias, behind BAR

  const int tid  = threadIdx.x;
  const int lane = tid & 63;
  const int w    = tid >> 6;   // wave 0..11
  const int c    = lane & 15;
  const int g    = lane >> 4;
  const int cx   = c & 7;
  const int bg   = blockIdx.x;

  const f32x4 zf = {0.f, 0.f, 0.f, 0.f};

  // ---- stage x fp32 -> bf16 -> LDS (once, persistent) ----
  {
    const float4* xg = (const float4*)(x + (size_t)bg * 24576);
#pragma unroll
    for (int it = 0; it < 4; ++it) {
      int hc  = tid + it * 768;          // 16B(bf16)-chunk id, 48 per row
      int row = hc / 48;
      int ch  = hc - row * 48;
      float4 v0 = xg[hc * 2];
      float4 v1 = xg[hc * 2 + 1];
      union { bf16_t b[8]; bf16x8 v; } pk;
      pk.b[0] = (bf16_t)v0.x; pk.b[1] = (bf16_t)v0.y;
      pk.b[2] = (bf16_t)v0.z; pk.b[3] = (bf16_t)v0.w;
      pk.b[4] = (bf16_t)v1.x; pk.b[5] = (bf16_t)v1.y;
      pk.b[6] = (bf16_t)v1.z; pk.b[7] = (bf16_t)v1.w;
      *(bf16x8*)(xs + row * 384 + ((ch ^ (row & 7)) << 3)) = pk.v;
    }
  }
  BAR();   // x visible (persists; never re-staged)

#pragma unroll 1
  for (int pass = 0; pass < 3; ++pass) {
    // ---------------- QKV GEMM: wave owns 2 n-tiles of 16 ------------------
    // kind wave-uniform: w0-3 Q, w4-7 K, w8-11 V. MFMA(a,bc): D[tok][n].
    f32x4 acc[2][4];
#pragma unroll
    for (int t = 0; t < 2; ++t)
#pragma unroll
      for (int mt = 0; mt < 4; ++mt) acc[t][mt] = zf;

    const int kind = (w * 2) >> 3;
    int nrow[2], hlv[2], c16v[2];
    const bf16_t* wp[2];
    float bv[2];
#pragma unroll
    for (int t = 0; t < 2; ++t) {
      int tau  = w * 2 + t;              // 0..23
      int u    = tau & 7;
      hlv[t]   = u >> 1;
      c16v[t]  = u & 1;
      nrow[t]  = kind * 384 + (pass * 4 + hlv[t]) * 32 + c16v[t] * 16;
      wp[t]    = wT + (size_t)(nrow[t] + c) * 384 + g * 8;
      bv[t]    = qbias[nrow[t] + c];
    }
    bf16x8 bc[2], bn[2];
#pragma unroll
    for (int t = 0; t < 2; ++t) bc[t] = *(const bf16x8*)(wp[t]);

#pragma unroll
    for (int k = 0; k < 12; ++k) {
      if (k < 11) {
#pragma unroll
        for (int t = 0; t < 2; ++t) bn[t] = *(const bf16x8*)(wp[t] + (k + 1) * 32);
      }
      int chv = (((4 * k + g) ^ cx) << 3);
#pragma unroll
      for (int mt = 0; mt < 4; ++mt) {   // rotating x-fragment
        bf16x8 a = *(const bf16x8*)(xs + (mt * 16 + c) * 384 + chv);
#pragma unroll
        for (int t = 0; t < 2; ++t)
          acc[t][mt] = MFMA16(a, bc[t], acc[t][mt]);
      }
#pragma unroll
      for (int t = 0; t < 2; ++t) bc[t] = bn[t];
    }

    BAR();   // prev pass attention (incl. ps=qs writes) complete

    // ---------------- epilogue: Q/K/V -> LDS (wave-uniform kind) -----------
#pragma unroll
    for (int t = 0; t < 2; ++t) {
      int hl = hlv[t], c16 = c16v[t];
      if (kind == 2) {                   // V^T [hl][d][tok], chunk ^= d&7
        int d = c16 * 16 + c;
        bf16_t* vbase = vts + hl * 2048 + d * 64;
#pragma unroll
        for (int mt = 0; mt < 4; ++mt) {
          union { bf16_t b[4]; uint2 u2; } pk;
#pragma unroll
          for (int r = 0; r < 4; ++r) pk.b[r] = (bf16_t)(acc[t][mt][r] + bv[t]);
          int chunk = (2 * mt + (g >> 1)) ^ cx;
          *(uint2*)(vbase + chunk * 8 + (g & 1) * 4) = pk.u2;
        }
      } else {                           // Q/K [hl][tok][32], swizzle v2
        int f  = c16 * 16 + c;
        int fc = f >> 3;
        int fl = f & 7;
        bf16_t* dst = (kind == 0 ? qs : ks) + hl * 2048;
#pragma unroll
        for (int mt = 0; mt < 4; ++mt)
#pragma unroll
          for (int r = 0; r < 4; ++r)
            dst[(mt * 16 + g * 4 + r) * 32 + ((fc ^ g) << 3) + fl] =
                (bf16_t)(acc[t][mt][r] + bv[t]);
      }
    }
    BAR();   // QKV visible

    // ---------------- attention: waves 0-7; ALL frag loads before ps alias -
    const int hl = w >> 1, ih = w & 1;
    const int h  = pass * 4 + hl;
    const int rsw = (c >> 2) & 3;
    bf16x8 ka[4], qf[2], va[2][2];
    if (w < 8) {
#pragma unroll
      for (int mt = 0; mt < 4; ++mt)
        ka[mt] = *(const bf16x8*)(ks + hl * 2048 + (mt * 16 + c) * 32 +
                                  ((g ^ rsw) << 3));
#pragma unroll
      for (int nt = 0; nt < 2; ++nt)
        qf[nt] = *(const bf16x8*)(qs + hl * 2048 +
                                  (ih * 32 + nt * 16 + c) * 32 + ((g ^ rsw) << 3));
#pragma unroll
      for (int m2 = 0; m2 < 2; ++m2)
#pragma unroll
        for (int kt = 0; kt < 2; ++kt)
          va[m2][kt] = *(const bf16x8*)(vts + hl * 2048 + (m2 * 16 + c) * 64 +
                                        (((4 * kt + g) ^ cx) << 3));
    }
    BAR();   // all qs/ks/vts fragment reads done -> ps may overwrite qs

    if (w < 8) {
      const bf16_t* bp = biasx + h * 4096;
      bf16_t* psw = ps + w * 1024;       // [16][64]

#pragma unroll
      for (int nt = 0; nt < 2; ++nt) {
        int i = ih * 32 + nt * 16 + c;

        f32x4 sacc[4];
#pragma unroll
        for (int mt = 0; mt < 4; ++mt) sacc[mt] = zf;
#pragma unroll
        for (int mt = 0; mt < 4; ++mt)
          sacc[mt] = MFMA16(ka[mt], qf[nt], sacc[mt]);

        // no-max softmax (|s|<~2; exp2 fp32-safe); P -> psw
        float l = 0.f;
#pragma unroll
        for (int mt = 0; mt < 4; ++mt) {
          uint2 bb = *(const uint2*)(bp + i * 64 + mt * 16 + g * 4);
          float p0 = exp2f((sacc[mt][0] + bflo(bb.x)) * LOG2E);
          float p1 = exp2f((sacc[mt][1] + bfhi(bb.x)) * LOG2E);
          float p2 = exp2f((sacc[mt][2] + bflo(bb.y)) * LOG2E);
          float p3 = exp2f((sacc[mt][3] + bfhi(bb.y)) * LOG2E);
          l += (p0 + p1) + (p2 + p3);
          union { bf16_t b[4]; uint2 u2; } pk;
          pk.b[0] = (bf16_t)p0; pk.b[1] = (bf16_t)p1;
          pk.b[2] = (bf16_t)p2; pk.b[3] = (bf16_t)p3;
          int chunk = (2 * mt + (g >> 1)) ^ cx;
          *(uint2*)(psw + c * 64 + chunk * 8 + (g & 1) * 4) = pk.u2;
        }
        bf16x8 pb[2];
#pragma unroll
        for (int kt = 0; kt < 2; ++kt)
          pb[kt] = *(const bf16x8*)(psw + c * 64 + (((4 * kt + g) ^ cx) << 3));
        f32x4 oacc[2];
#pragma unroll
        for (int m2 = 0; m2 < 2; ++m2) oacc[m2] = zf;
#pragma unroll
        for (int m2 = 0; m2 < 2; ++m2)
#pragma unroll
          for (int kt = 0; kt < 2; ++kt)
            oacc[m2] = MFMA16(va[m2][kt], pb[kt], oacc[m2]);

        l += __shfl_xor(l, 16);
        l += __shfl_xor(l, 32);
        float inv = 1.0f / l;

        // write to ao LDS, stage-swizzled: elem col = h*32 + m2*16 + g*4
#pragma unroll
        for (int m2 = 0; m2 < 2; ++m2) {
          union { bf16_t b[4]; uint2 u2; } pk;
#pragma unroll
          for (int r = 0; r < 4; ++r) pk.b[r] = (bf16_t)(oacc[m2][r] * inv);
          int ch = (h * 32 + m2 * 16 + g * 4) >> 3;
          *(uint2*)(ao + i * 384 + ((ch ^ (i & 7)) << 3) + (g & 1) * 4) = pk.u2;
        }
      }
    }
  }  // pass loop

  BAR();   // all ao writes visible

  // ---------------- merge GEMM: out = ao @ merge_wT + mb (fp32) ------------
  {
    f32x4 acc[2][4];
#pragma unroll
    for (int t = 0; t < 2; ++t)
#pragma unroll
      for (int mt = 0; mt < 4; ++mt) acc[t][mt] = zf;

    int n0[2];
    const bf16_t* wp[2];
    float mbv[2];
#pragma unroll
    for (int t = 0; t < 2; ++t) {
      n0[t] = (w * 2 + t) * 16;
      wp[t] = mwT + (size_t)(n0[t] + c) * 384 + g * 8;
      mbv[t] = mb[n0[t] + c];
    }
    bf16x8 bc[2], bn[2];
#pragma unroll
    for (int t = 0; t < 2; ++t) bc[t] = *(const bf16x8*)(wp[t]);

#pragma unroll
    for (int k = 0; k < 12; ++k) {
      if (k < 11) {
#pragma unroll
        for (int t = 0; t < 2; ++t) bn[t] = *(const bf16x8*)(wp[t] + (k + 1) * 32);
      }
      int chv = (((4 * k + g) ^ cx) << 3);
#pragma unroll
      for (int mt = 0; mt < 4; ++mt) {
        bf16x8 a = *(const bf16x8*)(ao + (mt * 16 + c) * 384 + chv);
#pragma unroll
        for (int t = 0; t < 2; ++t)
          acc[t][mt] = MFMA16(a, bc[t], acc[t][mt]);
      }
#pragma unroll
      for (int t = 0; t < 2; ++t) bc[t] = bn[t];
    }

    // out[tok][n]: lane -> tok = mt*16+g*4+r, n = n0+c (64B segments/quad)
#pragma unroll
    for (int t = 0; t < 2; ++t)
#pragma unroll
      for (int mt = 0; mt < 4; ++mt)
#pragma unroll
        for (int r = 0; r < 4; ++r)
          out[(size_t)(bg * 64 + mt * 16 + g * 4 + r) * 384 + n0[t] + c] =
              acc[t][mt][r] + mbv[t];
  }
}

// ---------------------------------------------------------------------------
extern "C" void kernel_launch(void* const* d_in, const int* in_sizes, int n_in,
                              void* d_out, int out_size, void* d_ws, size_t ws_size,
                              hipStream_t stream) {
  const float* x          = (const float*)d_in[0];
  const float* qkv_w      = (const float*)d_in[1];
  const float* qkv_b      = (const float*)d_in[2];
  const float* merge_w    = (const float*)d_in[3];
  const float* merge_b    = (const float*)d_in[4];
  const float* bias_table = (const float*)d_in[5];
  const int*   rel_index  = (const int*)d_in[6];
  float*       out        = (float*)d_out;

  const size_t OFF_QKVWT = 0;                       // 1152*384*2   = 884736
  const size_t OFF_MWT   = 884736;                  // 384*384*2    = 294912
  const size_t OFF_BIAS  = OFF_MWT + 294912;        // 12*64*64*2   = 98304
  const size_t OFF_QB    = OFF_BIAS + 98304;        // 1152*4       = 4608
  const size_t NEED      = OFF_QB + 4608;
  if (ws_size < NEED) return;

  char* ws = (char*)d_ws;
  bf16_t* qkv_wT  = (bf16_t*)(ws + OFF_QKVWT);
  bf16_t* mwT     = (bf16_t*)(ws + OFF_MWT);
  bf16_t* biasx   = (bf16_t*)(ws + OFF_BIAS);
  float*  qkvb_s  = (float*)(ws + OFF_QB);

  prep_kernel<<<2501, 256, 0, stream>>>(qkv_w, qkv_b, merge_w, bias_table,
                                        rel_index, qkv_wT, mwT, biasx, qkvb_s);

  hipFuncSetAttribute(reinterpret_cast<const void*>(mega_kernel),
                      hipFuncAttributeMaxDynamicSharedMemorySize, 147456);
  mega_kernel<<<2048, 768, 147456, stream>>>(x, qkv_wT, qkvb_s, biasx, mwT,
                                             merge_b, out);
}

// Round 17
// 512.632 us; speedup vs baseline: 1.3211x; 1.3211x over previous
//
#include <hip/hip_runtime.h>
#include <hip/hip_bf16.h>
#include <cstdint>
#include <cstddef>

// ---------------------------------------------------------------------------
// RelativePositionMultiHeadAttention  (B=32,G=64,P=64,D=384,H=12,DH=32)
// R17: DE-FUSE. Three streaming kernels (merge_gemm proved the machine does
//   this tile shape at ~5 TB/s without a mid-kernel phase chain):
//   1) qkv_gemm (bg,kind): Q->ws  [bg][h][tok][32]
//                          K->d_out[0..100MB] same layout
//                          V^T->d_out[100..201MB] [bg][h][d][64]
//      (d_out dead until merge; K+V = 201326592 B = exactly sizeof(out))
//   2) attn: 12288 blocks x 4 independent waves, ZERO barriers, frags from
//      global (L2), per-wave LDS P-scratch, no-max softmax, O written
//      IN-PLACE into the Q slice (qf loads data-precede O writes).
//   3) merge_gemm: stages from Q-region layout, writes d_out last.
//   ws NEED unchanged at 101.9 MB (proven budget).
// ---------------------------------------------------------------------------

typedef __bf16 bf16_t;
typedef __bf16 bf16x8 __attribute__((ext_vector_type(8)));
typedef float  f32x4  __attribute__((ext_vector_type(4)));

#define MFMA16(A, B, C) __builtin_amdgcn_mfma_f32_16x16x32_bf16((A), (B), (C), 0, 0, 0)

#define SCALE  0.051031036307982884f  // 384^-0.5
#define LOG2E  1.4426950408889634f

#define BAR()  do { asm volatile("s_waitcnt lgkmcnt(0)" ::: "memory"); \
                    __builtin_amdgcn_s_barrier(); } while (0)

// ---------------------------------------------------------------------------
__global__ void prep_kernel(const float* __restrict__ qkv_w,
                            const float* __restrict__ qkv_b,
                            const float* __restrict__ merge_w,
                            const float* __restrict__ bias_table,
                            const int*   __restrict__ rel_index,
                            bf16_t* __restrict__ qkv_wT,
                            bf16_t* __restrict__ merge_wT,
                            bf16_t* __restrict__ biasx,
                            float*  __restrict__ qkvb_s) {
  int idx = blockIdx.x * 256 + threadIdx.x;
  if (idx < 1152 * 384) {               // qkv_wT[n][k] = qkv_w[k][n] (*scale for K)
    int n = idx / 384, k = idx - n * 384;
    float v = qkv_w[k * 1152 + n];
    if (n >= 384 && n < 768) v *= SCALE;
    qkv_wT[idx] = (bf16_t)v;
    return;
  }
  int i2 = idx - 1152 * 384;
  if (i2 < 384 * 384) {                 // merge_wT[n][k] = merge_w[k][n]
    int n = i2 / 384, k = i2 - n * 384;
    merge_wT[i2] = (bf16_t)merge_w[k * 384 + n];
    return;
  }
  int i3 = i2 - 384 * 384;
  if (i3 < 12 * 64 * 64) {              // biasx[h][i*64+j], bf16
    int h = i3 / 4096, r = i3 - h * 4096;
    biasx[i3] = (bf16_t)bias_table[rel_index[r] * 12 + h];
    return;
  }
  int i4 = i3 - 12 * 64 * 64;
  if (i4 < 1152) {
    float v = qkv_b[i4];
    if (i4 >= 384 && i4 < 768) v *= SCALE;
    qkvb_s[i4] = v;
  }
}

__device__ inline float bflo(unsigned u) {
  union { unsigned x; float f; } v; v.x = u << 16; return v.f;
}
__device__ inline float bfhi(unsigned u) {
  union { unsigned x; float f; } v; v.x = u & 0xffff0000u; return v.f;
}

// ---------------------------------------------------------------------------
// qkv_gemm: grid 6144 = (bg, kind). 512 thr, 48 KB LDS. Stage x -> BAR ->
// 24 n-tiles (3/wave) -> write attention-native layouts. 2 barriers total.
// ---------------------------------------------------------------------------
__global__ void __launch_bounds__(512, 4)
qkv_gemm(const float*  __restrict__ x,
         const bf16_t* __restrict__ wT,
         const float*  __restrict__ qbias,
         bf16_t* __restrict__ qws,    // Q  [bg][h][64][32]
         bf16_t* __restrict__ kws,    // K  [bg][h][64][32]  (d_out lo)
         bf16_t* __restrict__ vws) {  // V^T[bg][h][32][64]  (d_out hi)
  extern __shared__ char smem_raw[];
  bf16_t* xs = (bf16_t*)smem_raw;     // [64][384] chunk^=(row&7)

  const int tid  = threadIdx.x;
  const int lane = tid & 63;
  const int w    = tid >> 6;   // wave 0..7
  const int c    = lane & 15;
  const int g    = lane >> 4;
  const int cx   = c & 7;

  // same-bg siblings (3 kinds) on same XCD -> x L2-shared (R9-proven)
  const int xcd  = blockIdx.x & 7;
  const int slot = blockIdx.x >> 3;
  const int kind = slot % 3;
  const int bg   = (slot / 3) * 8 + xcd;

  const f32x4 zf = {0.f, 0.f, 0.f, 0.f};

  // ---- stage x fp32 -> bf16 -> LDS: FIRST code ----
  {
    const float4* xg = (const float4*)(x + (size_t)bg * 24576);
#pragma unroll
    for (int it = 0; it < 6; ++it) {
      int hc  = tid + it * 512;          // 16B-chunk id, 48/row
      int row = hc / 48;
      int ch  = hc - row * 48;
      float4 v0 = xg[hc * 2];
      float4 v1 = xg[hc * 2 + 1];
      union { bf16_t b[8]; bf16x8 v; } pk;
      pk.b[0] = (bf16_t)v0.x; pk.b[1] = (bf16_t)v0.y;
      pk.b[2] = (bf16_t)v0.z; pk.b[3] = (bf16_t)v0.w;
      pk.b[4] = (bf16_t)v1.x; pk.b[5] = (bf16_t)v1.y;
      pk.b[6] = (bf16_t)v1.z; pk.b[7] = (bf16_t)v1.w;
      *(bf16x8*)(xs + row * 384 + ((ch ^ (row & 7)) << 3)) = pk.v;
    }
  }
  BAR();   // x visible

  f32x4 acc[3][4];
#pragma unroll
  for (int t = 0; t < 3; ++t)
#pragma unroll
    for (int mt = 0; mt < 4; ++mt) acc[t][mt] = zf;

  int tau[3];
  const bf16_t* wp[3];
#pragma unroll
  for (int t = 0; t < 3; ++t) {
    tau[t] = w * 3 + t;                  // 0..23, n0 = tau*16 within kind
    wp[t]  = wT + (size_t)(kind * 384 + tau[t] * 16 + c) * 384 + g * 8;
  }
  bf16x8 bc[3], bn[3];
#pragma unroll
  for (int t = 0; t < 3; ++t) bc[t] = *(const bf16x8*)(wp[t]);

  if (kind < 2) {
    // swapped: D[n][tok] -> lane: tok = mt*16+c, d-quad = (tau&1)*16 + g*4
    float4 qb4[3];
#pragma unroll
    for (int t = 0; t < 3; ++t)
      qb4[t] = *(const float4*)(qbias + kind * 384 + tau[t] * 16 + g * 4);
#pragma unroll
    for (int k = 0; k < 12; ++k) {
      if (k < 11) {
#pragma unroll
        for (int t = 0; t < 3; ++t) bn[t] = *(const bf16x8*)(wp[t] + (k + 1) * 32);
      }
      int chv = (((4 * k + g) ^ cx) << 3);
#pragma unroll
      for (int mt = 0; mt < 4; ++mt) {
        bf16x8 a = *(const bf16x8*)(xs + (mt * 16 + c) * 384 + chv);
#pragma unroll
        for (int t = 0; t < 3; ++t)
          acc[t][mt] = MFMA16(bc[t], a, acc[t][mt]);
      }
#pragma unroll
      for (int t = 0; t < 3; ++t) bc[t] = bn[t];
    }
    bf16_t* dst0 = (kind == 0 ? qws : kws) + (size_t)bg * 24576;
#pragma unroll
    for (int t = 0; t < 3; ++t) {
      int h = tau[t] >> 1, c16 = tau[t] & 1;
      bf16_t* dst = dst0 + h * 2048 + c16 * 16 + g * 4;
#pragma unroll
      for (int mt = 0; mt < 4; ++mt) {
        union { bf16_t b[4]; uint2 u2; } pk;
        pk.b[0] = (bf16_t)(acc[t][mt][0] + qb4[t].x);
        pk.b[1] = (bf16_t)(acc[t][mt][1] + qb4[t].y);
        pk.b[2] = (bf16_t)(acc[t][mt][2] + qb4[t].z);
        pk.b[3] = (bf16_t)(acc[t][mt][3] + qb4[t].w);
        *(uint2*)(dst + (mt * 16 + c) * 32) = pk.u2;
      }
    }
  } else {
    // unswapped: D[tok][n] -> lane: d = (tau&1)*16+c, tok-quad = mt*16+g*4
    float bv[3];
#pragma unroll
    for (int t = 0; t < 3; ++t) bv[t] = qbias[768 + tau[t] * 16 + c];
#pragma unroll
    for (int k = 0; k < 12; ++k) {
      if (k < 11) {
#pragma unroll
        for (int t = 0; t < 3; ++t) bn[t] = *(const bf16x8*)(wp[t] + (k + 1) * 32);
      }
      int chv = (((4 * k + g) ^ cx) << 3);
#pragma unroll
      for (int mt = 0; mt < 4; ++mt) {
        bf16x8 a = *(const bf16x8*)(xs + (mt * 16 + c) * 384 + chv);
#pragma unroll
        for (int t = 0; t < 3; ++t)
          acc[t][mt] = MFMA16(a, bc[t], acc[t][mt]);
      }
#pragma unroll
      for (int t = 0; t < 3; ++t) bc[t] = bn[t];
    }
    bf16_t* dst0 = vws + (size_t)bg * 24576;
#pragma unroll
    for (int t = 0; t < 3; ++t) {
      int h = tau[t] >> 1, c16 = tau[t] & 1;
      bf16_t* dst = dst0 + h * 2048 + (c16 * 16 + c) * 64 + g * 4;
#pragma unroll
      for (int mt = 0; mt < 4; ++mt) {
        union { bf16_t b[4]; uint2 u2; } pk;
#pragma unroll
        for (int r = 0; r < 4; ++r) pk.b[r] = (bf16_t)(acc[t][mt][r] + bv[t]);
        *(uint2*)(dst + mt * 16) = pk.u2;
      }
    }
  }
}

// ---------------------------------------------------------------------------
// attn: grid 12288 = (bg, j); 256 thr = 4 independent waves; NO barriers.
// wave item = j*4+w -> (h = it>>1, ih = it&1). Frags from global (L2).
// O written in-place into the Q slice (read-before-write by data dep).
// ---------------------------------------------------------------------------
__global__ void __launch_bounds__(256, 6)
attn_kernel(bf16_t* __restrict__ qws,
            const bf16_t* __restrict__ kws,
            const bf16_t* __restrict__ vws,
            const bf16_t* __restrict__ biasx) {
  __shared__ bf16_t ps[4][1024];        // per-wave [16][64] P scratch

  const int tid  = threadIdx.x;
  const int lane = tid & 63;
  const int w    = tid >> 6;   // wave 0..3
  const int c    = lane & 15;
  const int g    = lane >> 4;
  const int cx   = c & 7;

  const int bg = blockIdx.x / 6;
  const int it = (blockIdx.x % 6) * 4 + w;
  const int h  = it >> 1, ih = it & 1;

  bf16_t*       qsl = qws + (size_t)bg * 24576 + h * 2048;
  const bf16_t* ksl = kws + (size_t)bg * 24576 + h * 2048;
  const bf16_t* vsl = vws + (size_t)bg * 24576 + h * 2048;
  const bf16_t* bp  = biasx + h * 4096;

  const f32x4 zf = {0.f, 0.f, 0.f, 0.f};

  // load ALL frags (Q rows read before any in-place O write)
  bf16x8 ka[4], qf[2], va[2][2];
#pragma unroll
  for (int mt = 0; mt < 4; ++mt)
    ka[mt] = *(const bf16x8*)(ksl + (mt * 16 + c) * 32 + g * 8);
#pragma unroll
  for (int nt = 0; nt < 2; ++nt)
    qf[nt] = *(const bf16x8*)(qsl + (ih * 32 + nt * 16 + c) * 32 + g * 8);
#pragma unroll
  for (int m2 = 0; m2 < 2; ++m2)
#pragma unroll
    for (int kt = 0; kt < 2; ++kt)
      va[m2][kt] = *(const bf16x8*)(vsl + (m2 * 16 + c) * 64 + (4 * kt + g) * 8);

  bf16_t* psw = ps[w];

#pragma unroll
  for (int nt = 0; nt < 2; ++nt) {
    int i = ih * 32 + nt * 16 + c;

    f32x4 sacc[4];
#pragma unroll
    for (int mt = 0; mt < 4; ++mt) sacc[mt] = zf;
#pragma unroll
    for (int mt = 0; mt < 4; ++mt)
      sacc[mt] = MFMA16(ka[mt], qf[nt], sacc[mt]);
    // lane holds S^T[j][i]: j = mt*16+g*4+r, i as above.

    // no-max softmax (|s|<~2; exp2 fp32-safe); P -> psw (proven swizzle)
    float l = 0.f;
#pragma unroll
    for (int mt = 0; mt < 4; ++mt) {
      uint2 bb = *(const uint2*)(bp + i * 64 + mt * 16 + g * 4);
      float p0 = exp2f((sacc[mt][0] + bflo(bb.x)) * LOG2E);
      float p1 = exp2f((sacc[mt][1] + bfhi(bb.x)) * LOG2E);
      float p2 = exp2f((sacc[mt][2] + bflo(bb.y)) * LOG2E);
      float p3 = exp2f((sacc[mt][3] + bfhi(bb.y)) * LOG2E);
      l += (p0 + p1) + (p2 + p3);
      union { bf16_t b[4]; uint2 u2; } pk;
      pk.b[0] = (bf16_t)p0; pk.b[1] = (bf16_t)p1;
      pk.b[2] = (bf16_t)p2; pk.b[3] = (bf16_t)p3;
      int chunk = (2 * mt + (g >> 1)) ^ cx;
      *(uint2*)(psw + c * 64 + chunk * 8 + (g & 1) * 4) = pk.u2;
    }
    // wave-local write->read: compiler inserts lgkmcnt ordering
    bf16x8 pb[2];
#pragma unroll
    for (int kt = 0; kt < 2; ++kt)
      pb[kt] = *(const bf16x8*)(psw + c * 64 + (((4 * kt + g) ^ cx) << 3));
    f32x4 oacc[2];
#pragma unroll
    for (int m2 = 0; m2 < 2; ++m2) oacc[m2] = zf;
#pragma unroll
    for (int m2 = 0; m2 < 2; ++m2)
#pragma unroll
      for (int kt = 0; kt < 2; ++kt)
        oacc[m2] = MFMA16(va[m2][kt], pb[kt], oacc[m2]);

    l += __shfl_xor(l, 16);
    l += __shfl_xor(l, 32);
    float inv = 1.0f / l;

    // O in-place into Q slice rows i (wave-owned; qf already consumed)
#pragma unroll
    for (int m2 = 0; m2 < 2; ++m2) {
      union { bf16_t b[4]; uint2 u2; } pk;
#pragma unroll
      for (int r = 0; r < 4; ++r) pk.b[r] = (bf16_t)(oacc[m2][r] * inv);
      *(uint2*)(qsl + i * 32 + m2 * 16 + g * 4) = pk.u2;
    }
  }
}

// ---------------------------------------------------------------------------
// merge GEMM: out = attn(Q-region layout [bg][h][64][32]) @ mwT + mb, fp32.
// ---------------------------------------------------------------------------
#define XS 408
__global__ void __launch_bounds__(512)
merge_gemm(const bf16_t* __restrict__ aws,
           const bf16_t* __restrict__ mwT,
           const float*  __restrict__ mb,
           float* __restrict__ out) {
  __shared__ bf16_t as[64 * XS];
  const int tid = threadIdx.x, blk = blockIdx.x;
  const int lane = tid & 63, w = tid >> 6, c = lane & 15, g = lane >> 4;

  {
    const bf16_t* ag = aws + (size_t)blk * 24576;
#pragma unroll
    for (int it = 0; it < 6; ++it) {
      int idx = tid + it * 512;          // 0..3071 int4 chunks (8 bf16)
      int row = idx / 48;
      int ch  = idx - row * 48;          // 0..47: h = ch>>2, dp = (ch&3)*8
      int h   = ch >> 2;
      int dp  = (ch & 3) * 8;
      *(int4*)(as + row * XS + ch * 8) =
          *(const int4*)(ag + h * 2048 + row * 32 + dp);
    }
  }
  __syncthreads();

  const f32x4 zf = {0.f, 0.f, 0.f, 0.f};
  f32x4 acc[3][4];
#pragma unroll
  for (int t = 0; t < 3; ++t)
#pragma unroll
    for (int mt = 0; mt < 4; ++mt) acc[t][mt] = zf;

  const int n0 = w * 48;
  const bf16_t* wp[3];
#pragma unroll
  for (int t = 0; t < 3; ++t) wp[t] = mwT + (size_t)(n0 + t * 16 + c) * 384 + g * 8;
  bf16x8 bc[3], bn[3];
#pragma unroll
  for (int t = 0; t < 3; ++t) bc[t] = *(const bf16x8*)(wp[t]);
#pragma unroll
  for (int k = 0; k < 12; ++k) {
    if (k < 11) {
#pragma unroll
      for (int t = 0; t < 3; ++t) bn[t] = *(const bf16x8*)(wp[t] + (k + 1) * 32);
    }
    bf16x8 a[4];
#pragma unroll
    for (int mt = 0; mt < 4; ++mt)
      a[mt] = *(const bf16x8*)(as + (mt * 16 + c) * XS + k * 32 + g * 8);
#pragma unroll
    for (int t = 0; t < 3; ++t)
#pragma unroll
      for (int mt = 0; mt < 4; ++mt)
        acc[t][mt] = MFMA16(a[mt], bc[t], acc[t][mt]);
#pragma unroll
    for (int t = 0; t < 3; ++t) bc[t] = bn[t];
  }

#pragma unroll
  for (int t = 0; t < 3; ++t) {
    float bias = mb[n0 + t * 16 + c];
#pragma unroll
    for (int mt = 0; mt < 4; ++mt)
#pragma unroll
      for (int r = 0; r < 4; ++r)
        out[(size_t)(blk * 64 + mt * 16 + g * 4 + r) * 384 + n0 + t * 16 + c] =
            acc[t][mt][r] + bias;
  }
}

// ---------------------------------------------------------------------------
extern "C" void kernel_launch(void* const* d_in, const int* in_sizes, int n_in,
                              void* d_out, int out_size, void* d_ws, size_t ws_size,
                              hipStream_t stream) {
  const float* x          = (const float*)d_in[0];
  const float* qkv_w      = (const float*)d_in[1];
  const float* qkv_b      = (const float*)d_in[2];
  const float* merge_w    = (const float*)d_in[3];
  const float* merge_b    = (const float*)d_in[4];
  const float* bias_table = (const float*)d_in[5];
  const int*   rel_index  = (const int*)d_in[6];
  float*       out        = (float*)d_out;

  const size_t OFF_QKVWT = 0;                       // 1152*384*2   = 884736
  const size_t OFF_MWT   = 884736;                  // 384*384*2    = 294912
  const size_t OFF_BIAS  = OFF_MWT + 294912;        // 12*64*64*2   = 98304
  const size_t OFF_QB    = OFF_BIAS + 98304;        // 1152*4       = 4608
  const size_t OFF_QWS   = OFF_QB + 4608;           // 2048*12*2048*2 = 100663296
  const size_t NEED      = OFF_QWS + (size_t)100663296;
  if (ws_size < NEED) return;

  char* ws = (char*)d_ws;
  bf16_t* qkv_wT  = (bf16_t*)(ws + OFF_QKVWT);
  bf16_t* mwT     = (bf16_t*)(ws + OFF_MWT);
  bf16_t* biasx   = (bf16_t*)(ws + OFF_BIAS);
  float*  qkvb_s  = (float*)(ws + OFF_QB);
  bf16_t* qws     = (bf16_t*)(ws + OFF_QWS);
  // K and V^T live in d_out (201326592 B exactly); dead until merge writes.
  bf16_t* kws     = (bf16_t*)d_out;
  bf16_t* vws     = (bf16_t*)((char*)d_out + 100663296);

  prep_kernel<<<2501, 256, 0, stream>>>(qkv_w, qkv_b, merge_w, bias_table,
                                        rel_index, qkv_wT, mwT, biasx, qkvb_s);

  hipFuncSetAttribute(reinterpret_cast<const void*>(qkv_gemm),
                      hipFuncAttributeMaxDynamicSharedMemorySize, 49152);
  qkv_gemm<<<6144, 512, 49152, stream>>>(x, qkv_wT, qkvb_s, qws, kws, vws);

  attn_kernel<<<12288, 256, 0, stream>>>(qws, kws, vws, biasx);

  merge_gemm<<<2048, 512, 0, stream>>>(qws, mwT, merge_b, out);
}

// Round 18
// 506.009 us; speedup vs baseline: 1.3384x; 1.0131x over previous
//
#include <hip/hip_runtime.h>
#include <hip/hip_bf16.h>
#include <cstdint>
#include <cstddef>

// ---------------------------------------------------------------------------
// RelativePositionMultiHeadAttention  (B=32,G=64,P=64,D=384,H=12,DH=32)
// R18: FEWER, FATTER BLOCKS. R17 proved wall ~= Nblocks * T_block / conc with
//   T_block ~15-22us fixed latency (qkv_gemm 6144 blocks = 330us == fused;
//   merge 2048 blocks = 60us). Re-batch:
//   1) qkv_gemm3: 2048 blocks (one per bg); stage x ONCE (48KB LDS only ->
//      3 blocks/CU ceiling), unrolled kind-loop x3 reusing the tile; R17's
//      proven epilogues (Q->ws, K->d_out lo, V^T->d_out hi).
//   2) attn512: 2048 blocks x 8 waves x 3 items (was 12288x4x1); R17's
//      proven zero-barrier wave body; O in-place into Q region.
//   3) merge_gemm, prep unchanged.
// ---------------------------------------------------------------------------

typedef __bf16 bf16_t;
typedef __bf16 bf16x8 __attribute__((ext_vector_type(8)));
typedef float  f32x4  __attribute__((ext_vector_type(4)));

#define MFMA16(A, B, C) __builtin_amdgcn_mfma_f32_16x16x32_bf16((A), (B), (C), 0, 0, 0)

#define SCALE  0.051031036307982884f  // 384^-0.5
#define LOG2E  1.4426950408889634f

#define BAR()  do { asm volatile("s_waitcnt lgkmcnt(0)" ::: "memory"); \
                    __builtin_amdgcn_s_barrier(); } while (0)

// ---------------------------------------------------------------------------
__global__ void prep_kernel(const float* __restrict__ qkv_w,
                            const float* __restrict__ qkv_b,
                            const float* __restrict__ merge_w,
                            const float* __restrict__ bias_table,
                            const int*   __restrict__ rel_index,
                            bf16_t* __restrict__ qkv_wT,
                            bf16_t* __restrict__ merge_wT,
                            bf16_t* __restrict__ biasx,
                            float*  __restrict__ qkvb_s) {
  int idx = blockIdx.x * 256 + threadIdx.x;
  if (idx < 1152 * 384) {               // qkv_wT[n][k] = qkv_w[k][n] (*scale for K)
    int n = idx / 384, k = idx - n * 384;
    float v = qkv_w[k * 1152 + n];
    if (n >= 384 && n < 768) v *= SCALE;
    qkv_wT[idx] = (bf16_t)v;
    return;
  }
  int i2 = idx - 1152 * 384;
  if (i2 < 384 * 384) {                 // merge_wT[n][k] = merge_w[k][n]
    int n = i2 / 384, k = i2 - n * 384;
    merge_wT[i2] = (bf16_t)merge_w[k * 384 + n];
    return;
  }
  int i3 = i2 - 384 * 384;
  if (i3 < 12 * 64 * 64) {              // biasx[h][i*64+j], bf16
    int h = i3 / 4096, r = i3 - h * 4096;
    biasx[i3] = (bf16_t)bias_table[rel_index[r] * 12 + h];
    return;
  }
  int i4 = i3 - 12 * 64 * 64;
  if (i4 < 1152) {
    float v = qkv_b[i4];
    if (i4 >= 384 && i4 < 768) v *= SCALE;
    qkvb_s[i4] = v;
  }
}

__device__ inline float bflo(unsigned u) {
  union { unsigned x; float f; } v; v.x = u << 16; return v.f;
}
__device__ inline float bfhi(unsigned u) {
  union { unsigned x; float f; } v; v.x = u & 0xffff0000u; return v.f;
}

// ---------------------------------------------------------------------------
// qkv_gemm3: grid 2048 (one per bg). 512 thr, 48 KB LDS (x only).
// Stage x once -> BAR -> unrolled kind-loop x3 {GEMM -> direct global write}.
// ---------------------------------------------------------------------------
__global__ void __launch_bounds__(512, 4)
qkv_gemm3(const float*  __restrict__ x,
          const bf16_t* __restrict__ wT,
          const float*  __restrict__ qbias,
          bf16_t* __restrict__ qws,    // Q  [bg][h][64][32]
          bf16_t* __restrict__ kws,    // K  [bg][h][64][32]  (d_out lo)
          bf16_t* __restrict__ vws) {  // V^T[bg][h][32][64]  (d_out hi)
  extern __shared__ char smem_raw[];
  bf16_t* xs = (bf16_t*)smem_raw;     // [64][384] chunk^=(row&7)

  const int tid  = threadIdx.x;
  const int lane = tid & 63;
  const int w    = tid >> 6;   // wave 0..7
  const int c    = lane & 15;
  const int g    = lane >> 4;
  const int cx   = c & 7;
  const int bg   = blockIdx.x;

  const f32x4 zf = {0.f, 0.f, 0.f, 0.f};

  // ---- stage x fp32 -> bf16 -> LDS: FIRST code ----
  {
    const float4* xg = (const float4*)(x + (size_t)bg * 24576);
#pragma unroll
    for (int it = 0; it < 6; ++it) {
      int hc  = tid + it * 512;          // 16B-chunk id, 48/row
      int row = hc / 48;
      int ch  = hc - row * 48;
      float4 v0 = xg[hc * 2];
      float4 v1 = xg[hc * 2 + 1];
      union { bf16_t b[8]; bf16x8 v; } pk;
      pk.b[0] = (bf16_t)v0.x; pk.b[1] = (bf16_t)v0.y;
      pk.b[2] = (bf16_t)v0.z; pk.b[3] = (bf16_t)v0.w;
      pk.b[4] = (bf16_t)v1.x; pk.b[5] = (bf16_t)v1.y;
      pk.b[6] = (bf16_t)v1.z; pk.b[7] = (bf16_t)v1.w;
      *(bf16x8*)(xs + row * 384 + ((ch ^ (row & 7)) << 3)) = pk.v;
    }
  }
  BAR();   // x visible; persists for all three kinds

  int tau[3];
#pragma unroll
  for (int t = 0; t < 3; ++t) tau[t] = w * 3 + t;   // 0..23

#pragma unroll
  for (int kind = 0; kind < 3; ++kind) {
    f32x4 acc[3][4];
#pragma unroll
    for (int t = 0; t < 3; ++t)
#pragma unroll
      for (int mt = 0; mt < 4; ++mt) acc[t][mt] = zf;

    const bf16_t* wp[3];
#pragma unroll
    for (int t = 0; t < 3; ++t)
      wp[t] = wT + (size_t)(kind * 384 + tau[t] * 16 + c) * 384 + g * 8;
    bf16x8 bc[3], bn[3];
#pragma unroll
    for (int t = 0; t < 3; ++t) bc[t] = *(const bf16x8*)(wp[t]);

    if (kind < 2) {
      // swapped: D[n][tok] -> lane: tok = mt*16+c, d-quad = g*4 (+c16*16)
      float4 qb4[3];
#pragma unroll
      for (int t = 0; t < 3; ++t)
        qb4[t] = *(const float4*)(qbias + kind * 384 + tau[t] * 16 + g * 4);
#pragma unroll
      for (int k = 0; k < 12; ++k) {
        if (k < 11) {
#pragma unroll
          for (int t = 0; t < 3; ++t) bn[t] = *(const bf16x8*)(wp[t] + (k + 1) * 32);
        }
        int chv = (((4 * k + g) ^ cx) << 3);
#pragma unroll
        for (int mt = 0; mt < 4; ++mt) {
          bf16x8 a = *(const bf16x8*)(xs + (mt * 16 + c) * 384 + chv);
#pragma unroll
          for (int t = 0; t < 3; ++t)
            acc[t][mt] = MFMA16(bc[t], a, acc[t][mt]);
        }
#pragma unroll
        for (int t = 0; t < 3; ++t) bc[t] = bn[t];
      }
      bf16_t* dst0 = (kind == 0 ? qws : kws) + (size_t)bg * 24576;
#pragma unroll
      for (int t = 0; t < 3; ++t) {
        int h = tau[t] >> 1, c16 = tau[t] & 1;
        bf16_t* dst = dst0 + h * 2048 + c16 * 16 + g * 4;
#pragma unroll
        for (int mt = 0; mt < 4; ++mt) {
          union { bf16_t b[4]; uint2 u2; } pk;
          pk.b[0] = (bf16_t)(acc[t][mt][0] + qb4[t].x);
          pk.b[1] = (bf16_t)(acc[t][mt][1] + qb4[t].y);
          pk.b[2] = (bf16_t)(acc[t][mt][2] + qb4[t].z);
          pk.b[3] = (bf16_t)(acc[t][mt][3] + qb4[t].w);
          *(uint2*)(dst + (mt * 16 + c) * 32) = pk.u2;
        }
      }
    } else {
      // unswapped: D[tok][n] -> lane: d = c (+c16*16), tok-quad = mt*16+g*4
      float bv[3];
#pragma unroll
      for (int t = 0; t < 3; ++t) bv[t] = qbias[768 + tau[t] * 16 + c];
#pragma unroll
      for (int k = 0; k < 12; ++k) {
        if (k < 11) {
#pragma unroll
          for (int t = 0; t < 3; ++t) bn[t] = *(const bf16x8*)(wp[t] + (k + 1) * 32);
        }
        int chv = (((4 * k + g) ^ cx) << 3);
#pragma unroll
        for (int mt = 0; mt < 4; ++mt) {
          bf16x8 a = *(const bf16x8*)(xs + (mt * 16 + c) * 384 + chv);
#pragma unroll
          for (int t = 0; t < 3; ++t)
            acc[t][mt] = MFMA16(a, bc[t], acc[t][mt]);
        }
#pragma unroll
        for (int t = 0; t < 3; ++t) bc[t] = bn[t];
      }
      bf16_t* dst0 = vws + (size_t)bg * 24576;
#pragma unroll
      for (int t = 0; t < 3; ++t) {
        int h = tau[t] >> 1, c16 = tau[t] & 1;
        bf16_t* dst = dst0 + h * 2048 + (c16 * 16 + c) * 64 + g * 4;
#pragma unroll
        for (int mt = 0; mt < 4; ++mt) {
          union { bf16_t b[4]; uint2 u2; } pk;
#pragma unroll
          for (int r = 0; r < 4; ++r) pk.b[r] = (bf16_t)(acc[t][mt][r] + bv[t]);
          *(uint2*)(dst + mt * 16) = pk.u2;
        }
      }
    }
  }
}

// ---------------------------------------------------------------------------
// attn512: grid 2048 (one per bg); 512 thr = 8 waves x 3 items; NO barriers.
// item it = w*3+itl -> (h = it>>1, ih = it&1). Frags from global (L2).
// O in-place into Q slice (row-disjoint per (h,ih); q reads precede writes).
// ---------------------------------------------------------------------------
__global__ void __launch_bounds__(512, 4)
attn_kernel(bf16_t* __restrict__ qws,
            const bf16_t* __restrict__ kws,
            const bf16_t* __restrict__ vws,
            const bf16_t* __restrict__ biasx) {
  __shared__ bf16_t ps[8][1024];        // per-wave [16][64] P scratch

  const int tid  = threadIdx.x;
  const int lane = tid & 63;
  const int w    = tid >> 6;   // wave 0..7
  const int c    = lane & 15;
  const int g    = lane >> 4;
  const int cx   = c & 7;
  const int bg   = blockIdx.x;

  const f32x4 zf = {0.f, 0.f, 0.f, 0.f};
  bf16_t* psw = ps[w];

#pragma unroll 1
  for (int itl = 0; itl < 3; ++itl) {
    const int it = w * 3 + itl;          // 0..23
    const int h  = it >> 1, ih = it & 1;

    bf16_t*       qsl = qws + (size_t)bg * 24576 + h * 2048;
    const bf16_t* ksl = kws + (size_t)bg * 24576 + h * 2048;
    const bf16_t* vsl = vws + (size_t)bg * 24576 + h * 2048;
    const bf16_t* bp  = biasx + h * 4096;

    // load ALL frags (Q rows read before any in-place O write)
    bf16x8 ka[4], qf[2], va[2][2];
#pragma unroll
    for (int mt = 0; mt < 4; ++mt)
      ka[mt] = *(const bf16x8*)(ksl + (mt * 16 + c) * 32 + g * 8);
#pragma unroll
    for (int nt = 0; nt < 2; ++nt)
      qf[nt] = *(const bf16x8*)(qsl + (ih * 32 + nt * 16 + c) * 32 + g * 8);
#pragma unroll
    for (int m2 = 0; m2 < 2; ++m2)
#pragma unroll
      for (int kt = 0; kt < 2; ++kt)
        va[m2][kt] = *(const bf16x8*)(vsl + (m2 * 16 + c) * 64 + (4 * kt + g) * 8);

#pragma unroll
    for (int nt = 0; nt < 2; ++nt) {
      int i = ih * 32 + nt * 16 + c;

      f32x4 sacc[4];
#pragma unroll
      for (int mt = 0; mt < 4; ++mt) sacc[mt] = zf;
#pragma unroll
      for (int mt = 0; mt < 4; ++mt)
        sacc[mt] = MFMA16(ka[mt], qf[nt], sacc[mt]);
      // lane holds S^T[j][i]: j = mt*16+g*4+r.

      // no-max softmax (|s|<~2; exp2 fp32-safe); P -> psw (proven swizzle)
      float l = 0.f;
#pragma unroll
      for (int mt = 0; mt < 4; ++mt) {
        uint2 bb = *(const uint2*)(bp + i * 64 + mt * 16 + g * 4);
        float p0 = exp2f((sacc[mt][0] + bflo(bb.x)) * LOG2E);
        float p1 = exp2f((sacc[mt][1] + bfhi(bb.x)) * LOG2E);
        float p2 = exp2f((sacc[mt][2] + bflo(bb.y)) * LOG2E);
        float p3 = exp2f((sacc[mt][3] + bfhi(bb.y)) * LOG2E);
        l += (p0 + p1) + (p2 + p3);
        union { bf16_t b[4]; uint2 u2; } pk;
        pk.b[0] = (bf16_t)p0; pk.b[1] = (bf16_t)p1;
        pk.b[2] = (bf16_t)p2; pk.b[3] = (bf16_t)p3;
        int chunk = (2 * mt + (g >> 1)) ^ cx;
        *(uint2*)(psw + c * 64 + chunk * 8 + (g & 1) * 4) = pk.u2;
      }
      // wave-local write->read: compiler inserts lgkmcnt ordering
      bf16x8 pb[2];
#pragma unroll
      for (int kt = 0; kt < 2; ++kt)
        pb[kt] = *(const bf16x8*)(psw + c * 64 + (((4 * kt + g) ^ cx) << 3));
      f32x4 oacc[2];
#pragma unroll
      for (int m2 = 0; m2 < 2; ++m2) oacc[m2] = zf;
#pragma unroll
      for (int m2 = 0; m2 < 2; ++m2)
#pragma unroll
        for (int kt = 0; kt < 2; ++kt)
          oacc[m2] = MFMA16(va[m2][kt], pb[kt], oacc[m2]);

      l += __shfl_xor(l, 16);
      l += __shfl_xor(l, 32);
      float inv = 1.0f / l;

      // O in-place into Q slice rows i (item-owned; qf already consumed)
#pragma unroll
      for (int m2 = 0; m2 < 2; ++m2) {
        union { bf16_t b[4]; uint2 u2; } pk;
#pragma unroll
        for (int r = 0; r < 4; ++r) pk.b[r] = (bf16_t)(oacc[m2][r] * inv);
        *(uint2*)(qsl + i * 32 + m2 * 16 + g * 4) = pk.u2;
      }
    }
  }
}

// ---------------------------------------------------------------------------
// merge GEMM: out = attn(Q-region layout [bg][h][64][32]) @ mwT + mb, fp32.
// ---------------------------------------------------------------------------
#define XS 408
__global__ void __launch_bounds__(512)
merge_gemm(const bf16_t* __restrict__ aws,
           const bf16_t* __restrict__ mwT,
           const float*  __restrict__ mb,
           float* __restrict__ out) {
  __shared__ bf16_t as[64 * XS];
  const int tid = threadIdx.x, blk = blockIdx.x;
  const int lane = tid & 63, w = tid >> 6, c = lane & 15, g = lane >> 4;

  {
    const bf16_t* ag = aws + (size_t)blk * 24576;
#pragma unroll
    for (int it = 0; it < 6; ++it) {
      int idx = tid + it * 512;          // 0..3071 int4 chunks (8 bf16)
      int row = idx / 48;
      int ch  = idx - row * 48;          // h = ch>>2, dp = (ch&3)*8
      int h   = ch >> 2;
      int dp  = (ch & 3) * 8;
      *(int4*)(as + row * XS + ch * 8) =
          *(const int4*)(ag + h * 2048 + row * 32 + dp);
    }
  }
  __syncthreads();

  const f32x4 zf = {0.f, 0.f, 0.f, 0.f};
  f32x4 acc[3][4];
#pragma unroll
  for (int t = 0; t < 3; ++t)
#pragma unroll
    for (int mt = 0; mt < 4; ++mt) acc[t][mt] = zf;

  const int n0 = w * 48;
  const bf16_t* wp[3];
#pragma unroll
  for (int t = 0; t < 3; ++t) wp[t] = mwT + (size_t)(n0 + t * 16 + c) * 384 + g * 8;
  bf16x8 bc[3], bn[3];
#pragma unroll
  for (int t = 0; t < 3; ++t) bc[t] = *(const bf16x8*)(wp[t]);
#pragma unroll
  for (int k = 0; k < 12; ++k) {
    if (k < 11) {
#pragma unroll
      for (int t = 0; t < 3; ++t) bn[t] = *(const bf16x8*)(wp[t] + (k + 1) * 32);
    }
    bf16x8 a[4];
#pragma unroll
    for (int mt = 0; mt < 4; ++mt)
      a[mt] = *(const bf16x8*)(as + (mt * 16 + c) * XS + k * 32 + g * 8);
#pragma unroll
    for (int t = 0; t < 3; ++t)
#pragma unroll
      for (int mt = 0; mt < 4; ++mt)
        acc[t][mt] = MFMA16(a[mt], bc[t], acc[t][mt]);
#pragma unroll
    for (int t = 0; t < 3; ++t) bc[t] = bn[t];
  }

#pragma unroll
  for (int t = 0; t < 3; ++t) {
    float bias = mb[n0 + t * 16 + c];
#pragma unroll
    for (int mt = 0; mt < 4; ++mt)
#pragma unroll
      for (int r = 0; r < 4; ++r)
        out[(size_t)(blk * 64 + mt * 16 + g * 4 + r) * 384 + n0 + t * 16 + c] =
            acc[t][mt][r] + bias;
  }
}

// ---------------------------------------------------------------------------
extern "C" void kernel_launch(void* const* d_in, const int* in_sizes, int n_in,
                              void* d_out, int out_size, void* d_ws, size_t ws_size,
                              hipStream_t stream) {
  const float* x          = (const float*)d_in[0];
  const float* qkv_w      = (const float*)d_in[1];
  const float* qkv_b      = (const float*)d_in[2];
  const float* merge_w    = (const float*)d_in[3];
  const float* merge_b    = (const float*)d_in[4];
  const float* bias_table = (const float*)d_in[5];
  const int*   rel_index  = (const int*)d_in[6];
  float*       out        = (float*)d_out;

  const size_t OFF_QKVWT = 0;                       // 1152*384*2   = 884736
  const size_t OFF_MWT   = 884736;                  // 384*384*2    = 294912
  const size_t OFF_BIAS  = OFF_MWT + 294912;        // 12*64*64*2   = 98304
  const size_t OFF_QB    = OFF_BIAS + 98304;        // 1152*4       = 4608
  const size_t OFF_QWS   = OFF_QB + 4608;           // 2048*12*2048*2 = 100663296
  const size_t NEED      = OFF_QWS + (size_t)100663296;
  if (ws_size < NEED) return;

  char* ws = (char*)d_ws;
  bf16_t* qkv_wT  = (bf16_t*)(ws + OFF_QKVWT);
  bf16_t* mwT     = (bf16_t*)(ws + OFF_MWT);
  bf16_t* biasx   = (bf16_t*)(ws + OFF_BIAS);
  float*  qkvb_s  = (float*)(ws + OFF_QB);
  bf16_t* qws     = (bf16_t*)(ws + OFF_QWS);
  // K and V^T live in d_out (201326592 B exactly); dead until merge writes.
  bf16_t* kws     = (bf16_t*)d_out;
  bf16_t* vws     = (bf16_t*)((char*)d_out + 100663296);

  prep_kernel<<<2501, 256, 0, stream>>>(qkv_w, qkv_b, merge_w, bias_table,
                                        rel_index, qkv_wT, mwT, biasx, qkvb_s);

  hipFuncSetAttribute(reinterpret_cast<const void*>(qkv_gemm3),
                      hipFuncAttributeMaxDynamicSharedMemorySize, 49152);
  qkv_gemm3<<<2048, 512, 49152, stream>>>(x, qkv_wT, qkvb_s, qws, kws, vws);

  attn_kernel<<<2048, 512, 0, stream>>>(qws, kws, vws, biasx);

  merge_gemm<<<2048, 512, 0, stream>>>(qws, mwT, merge_b, out);
}